// Round 16
// baseline (4325.247 us; speedup 1.0000x reference)
//
#include <hip/hip_runtime.h>

typedef unsigned short ushort_t;
typedef _Float16 half_t;
typedef __attribute__((ext_vector_type(8))) _Float16 half8;
typedef __attribute__((ext_vector_type(4))) float f32x4;

#define B_ 256
#define T_ 200
#define X_ 128
#define H_ 512

// swizzled weight offsets in d_ws (f16 elements).
// Wu1/Wr1/Wn1 now cover K=[0,1024) only (x-part hoisted to xc prologue).
#define OFF_WO1 0
#define OFF_WO2 57344
#define OFF_WU1 122880
#define OFF_WR1 237568
#define OFF_WN1 352256
#define OFF_WU2 466944
#define OFF_WR2 532480
#define OFF_WN2 598016
#define OFF_WT1 729088
#define OFF_WT2 843776
#define OFF_WT3 858112
#define SWZ_TOTAL 989184
#define DTS_BYTE_OFF (SWZ_TOTAL * 2)
#define XC_BYTE_OFF (DTS_BYTE_OFF + 1024)
// xc: f32[(b*200 + t)*3 + gate][112], gates u=0,r=1,n=2 -> 68.8 MB in d_ws

#define LOG2E 1.4426950408889634f

struct Args {
  const float *x_data, *x_time;
  const float *Wu1, *bu1, *Wu2, *bu2;
  const float *Wr1, *br1, *Wr2, *br2;
  const float *Wn1, *bn1, *Wn2, *bn2;
  const float *Wo1, *bo1, *Wo2, *bo2;
  const float *Wt1, *bt1, *Wt2, *bt2, *Wt3, *bt3;
  float* out;      // f32 output: mu[256*512] then sigma[256*512]
  half_t* wsw;     // swizzled weights (f16)
  float* dts;      // 200 per-step dt values
  float* xc;       // precomputed x-contributions (u/r/n gates)
};

// hw-instruction activations (validated r12/r13: VALU -70%, absmax unchanged)
__device__ __forceinline__ float fast_sigm(float x) {
  return __builtin_amdgcn_rcpf(1.0f + __builtin_amdgcn_exp2f(-LOG2E * x));
}
__device__ __forceinline__ float fast_tanh(float x) {
  return 1.0f - 2.0f * __builtin_amdgcn_rcpf(1.0f + __builtin_amdgcn_exp2f((2.0f * LOG2E) * x));
}

// One 16x16 output tile, K = KB*32. A from LDS, B from pre-swizzled global.
// HARD CONSTRAINT (r12+r14+r15): compiler pins ~64 VGPRs for this 16-wave
// kernel; unroll >4, register A-caching, or extra live state spills to scratch
// (WRITE_SIZE balloons, dur +8..58%). Keep "#pragma unroll 4"; no new barriers.
template <int KB>
__device__ __forceinline__ f32x4 gemm_tile(const half_t* __restrict__ wtile,
                                           const half_t* __restrict__ abase,
                                           int astride, int lane, f32x4 acc) {
  const half_t* ap = abase + (lane & 15) * astride + 8 * (lane >> 4);
  const half_t* wp = wtile + lane * 8;
#pragma unroll 4
  for (int kb = 0; kb < KB; ++kb) {
    half8 af = *(const half8*)(ap + kb * 32);
    half8 bf = *(const half8*)(wp + kb * 512);
    acc = __builtin_amdgcn_mfma_f32_16x16x32_f16(af, bf, acc, 0, 0, 0);
  }
  return acc;
}

// Pre-swizzle f32 weights into f16 MFMA B-fragment layout, K padded to mult of
// 32 (zeros), N padded to mult of 16 (zeros). Wu1/Wr1/Wn1: K-rows [0,1024) only.
__global__ void swz_kernel(Args a) {
  struct WT { const float* src; int off; int KB; int Kr; int Nr; };
  const WT tbl[11] = {
      {a.Wo1, OFF_WO1, 16, 512, 100},  {a.Wo2, OFF_WO2, 4, 100, 512},
      {a.Wu1, OFF_WU1, 32, 1024, 100}, {a.Wr1, OFF_WR1, 32, 1024, 100},
      {a.Wn1, OFF_WN1, 32, 1024, 100}, {a.Wu2, OFF_WU2, 4, 100, 512},
      {a.Wr2, OFF_WR2, 4, 100, 512},   {a.Wn2, OFF_WN2, 4, 100, 1024},
      {a.Wt1, OFF_WT1, 32, 1024, 100}, {a.Wt2, OFF_WT2, 4, 100, 100},
      {a.Wt3, OFF_WT3, 4, 100, 1024}};
  const int ends[11] = {OFF_WO2, OFF_WU1, OFF_WR1, OFF_WN1, OFF_WU2, OFF_WR2,
                        OFF_WN2, OFF_WT1, OFF_WT2, OFF_WT3, SWZ_TOTAL};
  int gid = blockIdx.x * blockDim.x + threadIdx.x;
  int e8 = gid * 8;
  if (e8 >= SWZ_TOTAL) return;
  int w = 0;
  while (e8 >= ends[w]) ++w;
  const WT T = tbl[w];
  int local = e8 - T.off;
  int lane = (local >> 3) & 63;
  int blk = local >> 9;  // nt*KB + kb
  int kb = blk % T.KB, nt = blk / T.KB;
  int n = nt * 16 + (lane & 15);
  int k0 = kb * 32 + 8 * (lane >> 4);
#pragma unroll
  for (int j = 0; j < 8; ++j) {
    int k = k0 + j;
    float v = (k < T.Kr && n < T.Nr) ? T.src[k * T.Nr + n] : 0.0f;
    a.wsw[e8 + j] = (half_t)v;
  }
}

__global__ void dts_kernel(Args a) {
  int t = threadIdx.x;
  if (t >= T_) return;
  float v;
  if (t == 0)      v = -0.01f;
  else if (t == 1) v = a.x_time[T_ - 1] - a.x_time[0];
  else             v = a.x_time[t - 2] - a.x_time[t - 1];
  a.dts[t] = v;
}

// Prologue: xc[b][t][gate][n] = x_t[b] . W?1[1024+k][n]  (f32, all 256 CUs).
// block = (b, 20-step t-chunk); x-tile in LDS; weights L2-broadcast.
__global__ __launch_bounds__(256) void xprep_kernel(Args a) {
  __shared__ float xs[20][128];
  const int b = blockIdx.x, t0 = blockIdx.y * 20;
  for (int i = threadIdx.x; i < 20 * 128; i += 256) {
    int tt = i >> 7, k = i & 127;
    xs[tt][k] = a.x_data[((long)b * T_ + t0 + tt) * X_ + k];
  }
  __syncthreads();
  for (int o = threadIdx.x; o < 20 * 300; o += 256) {
    int tt = o / 300, rem = o % 300;
    int gate = rem / 100, n = rem % 100;
    const float* W = gate == 0 ? a.Wu1 : (gate == 1 ? a.Wr1 : a.Wn1);
    float s0 = 0.f, s1 = 0.f;
#pragma unroll 4
    for (int k = 0; k < 128; k += 2) {
      s0 += xs[tt][k] * W[(size_t)(1024 + k) * 100 + n];
      s1 += xs[tt][k + 1] * W[(size_t)(1025 + k) * 100 + n];
    }
    a.xc[(((long)b * T_ + t0 + tt) * 3 + gate) * 112 + n] = s0 + s1;
  }
}

// Persistent ODE-GRU scan: 16 blocks x 1024 threads; block b owns batch rows
// [16b,16b+16). State in registers at C-fragment positions:
//   hreg[s*4+i] = h[m=g*4+i][n=(wave+s*16)*16+lm]  (s=0,1)
// r16 = r13 structure (no split-K) with S3/S5 K shrunk 1152->1024 (x-part
// precomputed into xc, added in the f32 epilogue). S0 no longer stages x.
__global__ __launch_bounds__(1024) void odegru_kernel(Args a) {
  __shared__ __align__(16) half_t yc[16 * 1160];   // [h_ode | hs] (+c) - x part unused
  __shared__ __align__(16) half_t tg[16 * 136];
  __shared__ __align__(16) half_t tu[16 * 136];
  __shared__ __align__(16) half_t tr[16 * 136];
  __shared__ __align__(16) half_t tn[16 * 136];
  __shared__ float dts_s[T_];

  const int tid = threadIdx.x;
  const int wave = tid >> 6;
  const int lane = tid & 63;
  const int lm = lane & 15;
  const int g = lane >> 4;
  const int row0 = blockIdx.x * 16;

  for (int i = tid; i < 16 * 136; i += 1024) {
    tg[i] = (half_t)0.f; tu[i] = (half_t)0.f; tr[i] = (half_t)0.f; tn[i] = (half_t)0.f;
  }
  if (tid < T_) dts_s[tid] = a.dts[tid];

  float hreg[8], hsreg[8];
#pragma unroll
  for (int i = 0; i < 8; ++i) { hreg[i] = 0.f; hsreg[i] = 0.f; }
  float ureg[8];
  __syncthreads();

  for (int t = 0; t < T_; ++t) {
    const float dt = dts_s[t];
    // ---- S0: yc = [f16(h) | f16(hs)] ----
#pragma unroll
    for (int s = 0; s < 2; ++s) {
      int n = (wave + s * 16) * 16 + lm;
#pragma unroll
      for (int i = 0; i < 4; ++i) {
        int m = g * 4 + i;
        yc[m * 1160 + n]       = (half_t)hreg[s * 4 + i];
        yc[m * 1160 + 512 + n] = (half_t)hsreg[s * 4 + i];
      }
    }
    __syncthreads();
    // ---- S1: tg = tanh(h @ Wo1 + bo1) ----
    for (int nt = wave; nt < 7; nt += 16) {
      f32x4 acc = {0.f, 0.f, 0.f, 0.f};
      acc = gemm_tile<16>(a.wsw + OFF_WO1 + nt * 16 * 512, yc, 1160, lane, acc);
      int n = nt * 16 + lm;
      if (n < 100) {
        float bias = a.bo1[n];
#pragma unroll
        for (int i = 0; i < 4; ++i)
          tg[(g * 4 + i) * 136 + n] = (half_t)fast_tanh(acc[i] + bias);
      }
    }
    __syncthreads();
    // ---- S2: h_ode = h + dt*(tg @ Wo2 + bo2); hreg := h_ode; yc := f16(h_ode) ----
#pragma unroll
    for (int s = 0; s < 2; ++s) {
      int nt = wave + s * 16;
      f32x4 acc = {0.f, 0.f, 0.f, 0.f};
      acc = gemm_tile<4>(a.wsw + OFF_WO2 + nt * 4 * 512, tg, 136, lane, acc);
      int n = nt * 16 + lm;
      float bias = a.bo2[n];
#pragma unroll
      for (int i = 0; i < 4; ++i) {
        int m = g * 4 + i;
        float h_ode = hreg[s * 4 + i] + dt * (acc[i] + bias);
        hreg[s * 4 + i] = h_ode;
        yc[m * 1160 + n] = (half_t)h_ode;
      }
    }
    __syncthreads();
    // ---- S3: tu/tr = tanh([h_ode|hs]@W?1[0:1024] + xc + b) (14 tiles, K=1024) ----
    for (int nt = wave; nt < 14; nt += 16) {
      bool isU = nt < 7;
      int nt7 = isU ? nt : nt - 7;
      f32x4 acc = {0.f, 0.f, 0.f, 0.f};
      acc = gemm_tile<32>(a.wsw + (isU ? OFF_WU1 : OFF_WR1) + nt7 * 32 * 512, yc, 1160, lane, acc);
      int n = nt7 * 16 + lm;
      if (n < 100) {
        float bias = (isU ? a.bu1 : a.br1)[n];
        int gate = isU ? 0 : 1;
        half_t* dst = isU ? tu : tr;
#pragma unroll
        for (int i = 0; i < 4; ++i) {
          int m = g * 4 + i;
          float xv = a.xc[(((long)(row0 + m) * T_ + t) * 3 + gate) * 112 + n];
          dst[m * 136 + n] = (half_t)fast_tanh(acc[i] + xv + bias);
        }
      }
    }
    __syncthreads();
    // ---- S4: u -> ureg ; r -> fused c-build into yc ----
#pragma unroll
    for (int s = 0; s < 2; ++s) {
      int nt = wave + s * 16;
      f32x4 acc = {0.f, 0.f, 0.f, 0.f};
      acc = gemm_tile<4>(a.wsw + OFF_WU2 + nt * 4 * 512, tu, 136, lane, acc);
      int n = nt * 16 + lm;
      float bias = a.bu2[n];
#pragma unroll
      for (int i = 0; i < 4; ++i) ureg[s * 4 + i] = fast_sigm(acc[i] + bias);
    }
#pragma unroll
    for (int s = 0; s < 2; ++s) {
      int nt = wave + s * 16;
      f32x4 acc = {0.f, 0.f, 0.f, 0.f};
      acc = gemm_tile<4>(a.wsw + OFF_WR2 + nt * 4 * 512, tr, 136, lane, acc);
      int n = nt * 16 + lm;
      float bias = a.br2[n];
#pragma unroll
      for (int i = 0; i < 4; ++i) {
        int m = g * 4 + i;
        float r = fast_sigm(acc[i] + bias);
        yc[m * 1160 + n]       = (half_t)(hreg[s * 4 + i] * r);
        yc[m * 1160 + 512 + n] = (half_t)(hsreg[s * 4 + i] * r);
      }
    }
    __syncthreads();
    // ---- S5: tn = tanh([h r|hs r]@Wn1[0:1024] + xc + bn1) (K=1024) ----
    for (int nt = wave; nt < 7; nt += 16) {
      f32x4 acc = {0.f, 0.f, 0.f, 0.f};
      acc = gemm_tile<32>(a.wsw + OFF_WN1 + nt * 32 * 512, yc, 1160, lane, acc);
      int n = nt * 16 + lm;
      if (n < 100) {
        float bias = a.bn1[n];
#pragma unroll
        for (int i = 0; i < 4; ++i) {
          int m = g * 4 + i;
          float xv = a.xc[(((long)(row0 + m) * T_ + t) * 3 + 2) * 112 + n];
          tn[m * 136 + n] = (half_t)fast_tanh(acc[i] + xv + bias);
        }
      }
    }
    __syncthreads();
    // ---- S6: ns = tn @ Wn2 + bn2; gated state update in registers ----
#pragma unroll
    for (int s = 0; s < 4; ++s) {
      int nt = wave + s * 16;
      f32x4 acc = {0.f, 0.f, 0.f, 0.f};
      acc = gemm_tile<4>(a.wsw + OFF_WN2 + nt * 4 * 512, tn, 136, lane, acc);
      int n = nt * 16 + lm;
      float bias = a.bn2[n];
      if (s < 2) {  // m-part -> h update
#pragma unroll
        for (int i = 0; i < 4; ++i) {
          float u = ureg[s * 4 + i];
          float mval = acc[i] + bias;
          hreg[s * 4 + i] = (1.0f - u) * mval + u * hreg[s * 4 + i];
        }
      } else {      // s-part -> hs update (same n-tile as ureg[s-2])
#pragma unroll
        for (int i = 0; i < 4; ++i) {
          float u = ureg[(s - 2) * 4 + i];
          float sval = fabsf(acc[i] + bias);
          hsreg[(s - 2) * 4 + i] = (1.0f - u) * sval + u * hsreg[(s - 2) * 4 + i];
        }
      }
    }
    __syncthreads();
  }

  // ---- Final decoder ----
#pragma unroll
  for (int s = 0; s < 2; ++s) {
    int n = (wave + s * 16) * 16 + lm;
#pragma unroll
    for (int i = 0; i < 4; ++i) {
      int m = g * 4 + i;
      yc[m * 1160 + n]       = (half_t)hreg[s * 4 + i];
      yc[m * 1160 + 512 + n] = (half_t)hsreg[s * 4 + i];
    }
  }
  __syncthreads();
  for (int nt = wave; nt < 7; nt += 16) {  // z1 = tanh(hcat@Wt1+bt1)
    f32x4 acc = {0.f, 0.f, 0.f, 0.f};
    acc = gemm_tile<32>(a.wsw + OFF_WT1 + nt * 32 * 512, yc, 1160, lane, acc);
    int n = nt * 16 + lm;
    if (n < 100) {
      float bias = a.bt1[n];
#pragma unroll
      for (int i = 0; i < 4; ++i)
        tu[(g * 4 + i) * 136 + n] = (half_t)fast_tanh(acc[i] + bias);
    }
  }
  __syncthreads();
  for (int nt = wave; nt < 7; nt += 16) {  // z2 = tanh(z1@Wt2+bt2)
    f32x4 acc = {0.f, 0.f, 0.f, 0.f};
    acc = gemm_tile<4>(a.wsw + OFF_WT2 + nt * 4 * 512, tu, 136, lane, acc);
    int n = nt * 16 + lm;
    if (n < 100) {
      float bias = a.bt2[n];
#pragma unroll
      for (int i = 0; i < 4; ++i)
        tr[(g * 4 + i) * 136 + n] = (half_t)fast_tanh(acc[i] + bias);
    }
  }
  __syncthreads();
#pragma unroll
  for (int s = 0; s < 4; ++s) {  // z3 = z2@Wt3+bt3 -> mu | sigma (f32 out)
    int nt = wave + s * 16;
    f32x4 acc = {0.f, 0.f, 0.f, 0.f};
    acc = gemm_tile<4>(a.wsw + OFF_WT3 + nt * 4 * 512, tr, 136, lane, acc);
    int n = nt * 16 + lm;
    float bias = a.bt3[n];
#pragma unroll
    for (int i = 0; i < 4; ++i) {
      int grow = row0 + g * 4 + i;
      float val = acc[i] + bias;
      if (n < 512)
        a.out[(size_t)grow * 512 + n] = val;
      else
        a.out[(size_t)(B_ * 512) + (size_t)grow * 512 + (n - 512)] = fabsf(val);
    }
  }
}

extern "C" void kernel_launch(void* const* d_in, const int* in_sizes, int n_in,
                              void* d_out, int out_size, void* d_ws, size_t ws_size,
                              hipStream_t stream) {
  Args a;
  a.x_data = (const float*)d_in[0];
  a.x_time = (const float*)d_in[1];
  a.Wu1 = (const float*)d_in[2];  a.bu1 = (const float*)d_in[3];
  a.Wu2 = (const float*)d_in[4];  a.bu2 = (const float*)d_in[5];
  a.Wr1 = (const float*)d_in[6];  a.br1 = (const float*)d_in[7];
  a.Wr2 = (const float*)d_in[8];  a.br2 = (const float*)d_in[9];
  a.Wn1 = (const float*)d_in[10]; a.bn1 = (const float*)d_in[11];
  a.Wn2 = (const float*)d_in[12]; a.bn2 = (const float*)d_in[13];
  a.Wo1 = (const float*)d_in[14]; a.bo1 = (const float*)d_in[15];
  a.Wo2 = (const float*)d_in[16]; a.bo2 = (const float*)d_in[17];
  a.Wt1 = (const float*)d_in[18]; a.bt1 = (const float*)d_in[19];
  a.Wt2 = (const float*)d_in[20]; a.bt2 = (const float*)d_in[21];
  a.Wt3 = (const float*)d_in[22]; a.bt3 = (const float*)d_in[23];
  a.out = (float*)d_out;
  a.wsw = (half_t*)d_ws;
  a.dts = (float*)((char*)d_ws + DTS_BYTE_OFF);
  a.xc  = (float*)((char*)d_ws + XC_BYTE_OFF);

  swz_kernel<<<dim3(483), dim3(256), 0, stream>>>(a);
  dts_kernel<<<dim3(1), dim3(256), 0, stream>>>(a);
  xprep_kernel<<<dim3(B_, 10), dim3(256), 0, stream>>>(a);
  odegru_kernel<<<dim3(16), dim3(1024), 0, stream>>>(a);
}

// Round 17
// 3643.439 us; speedup vs baseline: 1.1871x; 1.1871x over previous
//
#include <hip/hip_runtime.h>

typedef unsigned short ushort_t;
typedef _Float16 half_t;
typedef __attribute__((ext_vector_type(8))) _Float16 half8;
typedef __attribute__((ext_vector_type(4))) float f32x4;

#define B_ 256
#define T_ 200
#define X_ 128
#define H_ 512

// swizzled weight offsets in d_ws (f16 elements)
#define OFF_WO1 0
#define OFF_WO2 57344
#define OFF_WU1 122880
#define OFF_WR1 251904
#define OFF_WN1 380928
#define OFF_WU2 509952
#define OFF_WR2 575488
#define OFF_WN2 641024
#define OFF_WT1 772096
#define OFF_WT2 886784
#define OFF_WT3 901120
#define SWZ_TOTAL 1032192
#define DTS_BYTE_OFF (SWZ_TOTAL * 2)

#define LOG2E 1.4426950408889634f

// ===== r17 = r13 verbatim (best verified: 3670 us). Experiment ledger: =====
//  r12/r14: unroll>4 or register A-caching -> compiler pins 64 VGPR, spills
//           (WRITE_SIZE 2.9->10-14 MB, +58%). CLOSED.
//  r15: split-K S1/S5 (+2 barriers) -> +8.5%. Barriers cost more than balance.
//  r16: x-part hoist (K 1152->1024 + xc epilogue loads) -> +5%. Scattered HBM
//       epilogue reads beat the saved MFMA issue. CLOSED.
//  Only wins: MFMA+LDS structure itself (r11) and fast transcendentals (r13).

struct Args {
  const float *x_data, *x_time;
  const float *Wu1, *bu1, *Wu2, *bu2;
  const float *Wr1, *br1, *Wr2, *br2;
  const float *Wn1, *bn1, *Wn2, *bn2;
  const float *Wo1, *bo1, *Wo2, *bo2;
  const float *Wt1, *bt1, *Wt2, *bt2, *Wt3, *bt3;
  float* out;      // f32 output: mu[256*512] then sigma[256*512]
  half_t* wsw;     // swizzled weights (f16)
  float* dts;      // 200 per-step dt values
};

// hw-instruction activations (validated r12/r13: VALU -70%, absmax unchanged)
__device__ __forceinline__ float fast_sigm(float x) {
  return __builtin_amdgcn_rcpf(1.0f + __builtin_amdgcn_exp2f(-LOG2E * x));
}
__device__ __forceinline__ float fast_tanh(float x) {
  return 1.0f - 2.0f * __builtin_amdgcn_rcpf(1.0f + __builtin_amdgcn_exp2f((2.0f * LOG2E) * x));
}

// One 16x16 output tile, K = KB*32. A from LDS, B from pre-swizzled global.
// Keep "#pragma unroll 4" (see ledger above).
template <int KB>
__device__ __forceinline__ f32x4 gemm_tile(const half_t* __restrict__ wtile,
                                           const half_t* __restrict__ abase,
                                           int astride, int lane, f32x4 acc) {
  const half_t* ap = abase + (lane & 15) * astride + 8 * (lane >> 4);
  const half_t* wp = wtile + lane * 8;
#pragma unroll 4
  for (int kb = 0; kb < KB; ++kb) {
    half8 af = *(const half8*)(ap + kb * 32);
    half8 bf = *(const half8*)(wp + kb * 512);
    acc = __builtin_amdgcn_mfma_f32_16x16x32_f16(af, bf, acc, 0, 0, 0);
  }
  return acc;
}

// Pre-swizzle f32 weights into f16 MFMA B-fragment layout, K padded to mult of
// 32 (zeros), N padded to mult of 16 (zeros).
__global__ void swz_kernel(Args a) {
  struct WT { const float* src; int off; int KB; int Kr; int Nr; };
  const WT tbl[11] = {
      {a.Wo1, OFF_WO1, 16, 512, 100},  {a.Wo2, OFF_WO2, 4, 100, 512},
      {a.Wu1, OFF_WU1, 36, 1152, 100}, {a.Wr1, OFF_WR1, 36, 1152, 100},
      {a.Wn1, OFF_WN1, 36, 1152, 100}, {a.Wu2, OFF_WU2, 4, 100, 512},
      {a.Wr2, OFF_WR2, 4, 100, 512},   {a.Wn2, OFF_WN2, 4, 100, 1024},
      {a.Wt1, OFF_WT1, 32, 1024, 100}, {a.Wt2, OFF_WT2, 4, 100, 100},
      {a.Wt3, OFF_WT3, 4, 100, 1024}};
  const int ends[11] = {OFF_WO2, OFF_WU1, OFF_WR1, OFF_WN1, OFF_WU2, OFF_WR2,
                        OFF_WN2, OFF_WT1, OFF_WT2, OFF_WT3, SWZ_TOTAL};
  int gid = blockIdx.x * blockDim.x + threadIdx.x;
  int e8 = gid * 8;
  if (e8 >= SWZ_TOTAL) return;
  int w = 0;
  while (e8 >= ends[w]) ++w;
  const WT T = tbl[w];
  int local = e8 - T.off;
  int lane = (local >> 3) & 63;
  int blk = local >> 9;  // nt*KB + kb
  int kb = blk % T.KB, nt = blk / T.KB;
  int n = nt * 16 + (lane & 15);
  int k0 = kb * 32 + 8 * (lane >> 4);
#pragma unroll
  for (int j = 0; j < 8; ++j) {
    int k = k0 + j;
    float v = (k < T.Kr && n < T.Nr) ? T.src[k * T.Nr + n] : 0.0f;
    a.wsw[e8 + j] = (half_t)v;
  }
}

__global__ void dts_kernel(Args a) {
  int t = threadIdx.x;
  if (t >= T_) return;
  float v;
  if (t == 0)      v = -0.01f;
  else if (t == 1) v = a.x_time[T_ - 1] - a.x_time[0];
  else             v = a.x_time[t - 2] - a.x_time[t - 1];
  a.dts[t] = v;
}

// Persistent ODE-GRU scan: 16 blocks x 1024 threads; block b owns batch rows
// [16b,16b+16). State in registers at C-fragment positions:
//   hreg[s*4+i] = h[m=g*4+i][n=(wave+s*16)*16+lm]  (s=0,1)
__global__ __launch_bounds__(1024) void odegru_kernel(Args a) {
  // yc stride 1160 f16 (=580 dw == 4 mod 32 -> 2-way-free LDS banks)
  __shared__ __align__(16) half_t yc[16 * 1160];   // [h_ode | hs | x] then c
  __shared__ __align__(16) half_t tg[16 * 136];
  __shared__ __align__(16) half_t tu[16 * 136];
  __shared__ __align__(16) half_t tr[16 * 136];
  __shared__ __align__(16) half_t tn[16 * 136];
  __shared__ float dts_s[T_];

  const int tid = threadIdx.x;
  const int wave = tid >> 6;
  const int lane = tid & 63;
  const int lm = lane & 15;
  const int g = lane >> 4;
  const int row0 = blockIdx.x * 16;

  for (int i = tid; i < 16 * 136; i += 1024) {
    tg[i] = (half_t)0.f; tu[i] = (half_t)0.f; tr[i] = (half_t)0.f; tn[i] = (half_t)0.f;
  }
  if (tid < T_) dts_s[tid] = a.dts[tid];

  float hreg[8], hsreg[8];
#pragma unroll
  for (int i = 0; i < 8; ++i) { hreg[i] = 0.f; hsreg[i] = 0.f; }
  float ureg[8];  // u gate: producer wave == consumer wave
  __syncthreads();

  for (int t = 0; t < T_; ++t) {
    const float dt = dts_s[t];
    // ---- S0: yc = [f16(h) | f16(hs) | f16(x_t)] ----
#pragma unroll
    for (int s = 0; s < 2; ++s) {
      int n = (wave + s * 16) * 16 + lm;
#pragma unroll
      for (int i = 0; i < 4; ++i) {
        int m = g * 4 + i;
        yc[m * 1160 + n]       = (half_t)hreg[s * 4 + i];
        yc[m * 1160 + 512 + n] = (half_t)hsreg[s * 4 + i];
      }
    }
    for (int i = tid; i < 16 * 128; i += 1024) {
      int m = i >> 7, xk = i & 127;
      yc[m * 1160 + 1024 + xk] = (half_t)a.x_data[((long)(row0 + m) * T_ + t) * X_ + xk];
    }
    __syncthreads();
    // ---- S1: tg = tanh(h @ Wo1 + bo1) ----
    for (int nt = wave; nt < 7; nt += 16) {
      f32x4 acc = {0.f, 0.f, 0.f, 0.f};
      acc = gemm_tile<16>(a.wsw + OFF_WO1 + nt * 16 * 512, yc, 1160, lane, acc);
      int n = nt * 16 + lm;
      if (n < 100) {
        float bias = a.bo1[n];
#pragma unroll
        for (int i = 0; i < 4; ++i)
          tg[(g * 4 + i) * 136 + n] = (half_t)fast_tanh(acc[i] + bias);
      }
    }
    __syncthreads();
    // ---- S2: h_ode = h + dt*(tg @ Wo2 + bo2); hreg := h_ode; yc := f16(h_ode) ----
#pragma unroll
    for (int s = 0; s < 2; ++s) {
      int nt = wave + s * 16;
      f32x4 acc = {0.f, 0.f, 0.f, 0.f};
      acc = gemm_tile<4>(a.wsw + OFF_WO2 + nt * 4 * 512, tg, 136, lane, acc);
      int n = nt * 16 + lm;
      float bias = a.bo2[n];
#pragma unroll
      for (int i = 0; i < 4; ++i) {
        int m = g * 4 + i;
        float h_ode = hreg[s * 4 + i] + dt * (acc[i] + bias);
        hreg[s * 4 + i] = h_ode;
        yc[m * 1160 + n] = (half_t)h_ode;
      }
    }
    __syncthreads();
    // ---- S3: tu = tanh(yc@Wu1+bu1), tr = tanh(yc@Wr1+br1) (14 tiles) ----
    for (int nt = wave; nt < 14; nt += 16) {
      bool isU = nt < 7;
      int nt7 = isU ? nt : nt - 7;
      f32x4 acc = {0.f, 0.f, 0.f, 0.f};
      acc = gemm_tile<36>(a.wsw + (isU ? OFF_WU1 : OFF_WR1) + nt7 * 36 * 512, yc, 1160, lane, acc);
      int n = nt7 * 16 + lm;
      if (n < 100) {
        float bias = (isU ? a.bu1 : a.br1)[n];
        half_t* dst = isU ? tu : tr;
#pragma unroll
        for (int i = 0; i < 4; ++i)
          dst[(g * 4 + i) * 136 + n] = (half_t)fast_tanh(acc[i] + bias);
      }
    }
    __syncthreads();
    // ---- S4: u -> ureg ; r -> fused c-build into yc ----
#pragma unroll
    for (int s = 0; s < 2; ++s) {
      int nt = wave + s * 16;
      f32x4 acc = {0.f, 0.f, 0.f, 0.f};
      acc = gemm_tile<4>(a.wsw + OFF_WU2 + nt * 4 * 512, tu, 136, lane, acc);
      int n = nt * 16 + lm;
      float bias = a.bu2[n];
#pragma unroll
      for (int i = 0; i < 4; ++i) ureg[s * 4 + i] = fast_sigm(acc[i] + bias);
    }
#pragma unroll
    for (int s = 0; s < 2; ++s) {
      int nt = wave + s * 16;
      f32x4 acc = {0.f, 0.f, 0.f, 0.f};
      acc = gemm_tile<4>(a.wsw + OFF_WR2 + nt * 4 * 512, tr, 136, lane, acc);
      int n = nt * 16 + lm;
      float bias = a.br2[n];
#pragma unroll
      for (int i = 0; i < 4; ++i) {
        int m = g * 4 + i;
        float r = fast_sigm(acc[i] + bias);
        yc[m * 1160 + n]       = (half_t)(hreg[s * 4 + i] * r);
        yc[m * 1160 + 512 + n] = (half_t)(hsreg[s * 4 + i] * r);
      }
    }
    __syncthreads();
    // ---- S5: tn = tanh(c @ Wn1 + bn1) ----
    for (int nt = wave; nt < 7; nt += 16) {
      f32x4 acc = {0.f, 0.f, 0.f, 0.f};
      acc = gemm_tile<36>(a.wsw + OFF_WN1 + nt * 36 * 512, yc, 1160, lane, acc);
      int n = nt * 16 + lm;
      if (n < 100) {
        float bias = a.bn1[n];
#pragma unroll
        for (int i = 0; i < 4; ++i)
          tn[(g * 4 + i) * 136 + n] = (half_t)fast_tanh(acc[i] + bias);
      }
    }
    __syncthreads();
    // ---- S6: ns = tn @ Wn2 + bn2; gated state update in registers ----
#pragma unroll
    for (int s = 0; s < 4; ++s) {
      int nt = wave + s * 16;
      f32x4 acc = {0.f, 0.f, 0.f, 0.f};
      acc = gemm_tile<4>(a.wsw + OFF_WN2 + nt * 4 * 512, tn, 136, lane, acc);
      int n = nt * 16 + lm;
      float bias = a.bn2[n];
      if (s < 2) {  // m-part -> h update
#pragma unroll
        for (int i = 0; i < 4; ++i) {
          float u = ureg[s * 4 + i];
          float mval = acc[i] + bias;
          hreg[s * 4 + i] = (1.0f - u) * mval + u * hreg[s * 4 + i];
        }
      } else {      // s-part -> hs update (same n-tile as ureg[s-2])
#pragma unroll
        for (int i = 0; i < 4; ++i) {
          float u = ureg[(s - 2) * 4 + i];
          float sval = fabsf(acc[i] + bias);
          hsreg[(s - 2) * 4 + i] = (1.0f - u) * sval + u * hsreg[(s - 2) * 4 + i];
        }
      }
    }
    __syncthreads();
  }

  // ---- Final decoder ----
#pragma unroll
  for (int s = 0; s < 2; ++s) {
    int n = (wave + s * 16) * 16 + lm;
#pragma unroll
    for (int i = 0; i < 4; ++i) {
      int m = g * 4 + i;
      yc[m * 1160 + n]       = (half_t)hreg[s * 4 + i];
      yc[m * 1160 + 512 + n] = (half_t)hsreg[s * 4 + i];
    }
  }
  __syncthreads();
  for (int nt = wave; nt < 7; nt += 16) {  // z1 = tanh(hcat@Wt1+bt1)
    f32x4 acc = {0.f, 0.f, 0.f, 0.f};
    acc = gemm_tile<32>(a.wsw + OFF_WT1 + nt * 32 * 512, yc, 1160, lane, acc);
    int n = nt * 16 + lm;
    if (n < 100) {
      float bias = a.bt1[n];
#pragma unroll
      for (int i = 0; i < 4; ++i)
        tu[(g * 4 + i) * 136 + n] = (half_t)fast_tanh(acc[i] + bias);
    }
  }
  __syncthreads();
  for (int nt = wave; nt < 7; nt += 16) {  // z2 = tanh(z1@Wt2+bt2)
    f32x4 acc = {0.f, 0.f, 0.f, 0.f};
    acc = gemm_tile<4>(a.wsw + OFF_WT2 + nt * 4 * 512, tu, 136, lane, acc);
    int n = nt * 16 + lm;
    if (n < 100) {
      float bias = a.bt2[n];
#pragma unroll
      for (int i = 0; i < 4; ++i)
        tr[(g * 4 + i) * 136 + n] = (half_t)fast_tanh(acc[i] + bias);
    }
  }
  __syncthreads();
#pragma unroll
  for (int s = 0; s < 4; ++s) {  // z3 = z2@Wt3+bt3 -> mu | sigma (f32 out)
    int nt = wave + s * 16;
    f32x4 acc = {0.f, 0.f, 0.f, 0.f};
    acc = gemm_tile<4>(a.wsw + OFF_WT3 + nt * 4 * 512, tr, 136, lane, acc);
    int n = nt * 16 + lm;
    float bias = a.bt3[n];
#pragma unroll
    for (int i = 0; i < 4; ++i) {
      int grow = row0 + g * 4 + i;
      float val = acc[i] + bias;
      if (n < 512)
        a.out[(size_t)grow * 512 + n] = val;
      else
        a.out[(size_t)(B_ * 512) + (size_t)grow * 512 + (n - 512)] = fabsf(val);
    }
  }
}

extern "C" void kernel_launch(void* const* d_in, const int* in_sizes, int n_in,
                              void* d_out, int out_size, void* d_ws, size_t ws_size,
                              hipStream_t stream) {
  Args a;
  a.x_data = (const float*)d_in[0];
  a.x_time = (const float*)d_in[1];
  a.Wu1 = (const float*)d_in[2];  a.bu1 = (const float*)d_in[3];
  a.Wu2 = (const float*)d_in[4];  a.bu2 = (const float*)d_in[5];
  a.Wr1 = (const float*)d_in[6];  a.br1 = (const float*)d_in[7];
  a.Wr2 = (const float*)d_in[8];  a.br2 = (const float*)d_in[9];
  a.Wn1 = (const float*)d_in[10]; a.bn1 = (const float*)d_in[11];
  a.Wn2 = (const float*)d_in[12]; a.bn2 = (const float*)d_in[13];
  a.Wo1 = (const float*)d_in[14]; a.bo1 = (const float*)d_in[15];
  a.Wo2 = (const float*)d_in[16]; a.bo2 = (const float*)d_in[17];
  a.Wt1 = (const float*)d_in[18]; a.bt1 = (const float*)d_in[19];
  a.Wt2 = (const float*)d_in[20]; a.bt2 = (const float*)d_in[21];
  a.Wt3 = (const float*)d_in[22]; a.bt3 = (const float*)d_in[23];
  a.out = (float*)d_out;
  a.wsw = (half_t*)d_ws;
  a.dts = (float*)((char*)d_ws + DTS_BYTE_OFF);

  swz_kernel<<<dim3(504), dim3(256), 0, stream>>>(a);
  dts_kernel<<<dim3(1), dim3(256), 0, stream>>>(a);
  odegru_kernel<<<dim3(16), dim3(1024), 0, stream>>>(a);
}